// Round 2
// baseline (355.257 us; speedup 1.0000x reference)
//
#include <hip/hip_runtime.h>
#include <math.h>

#define NODES 6272
#define BATCH 64
#define NCAPS 10
#define CIN   8
#define COUT  16
#define NW    16                 // nodes per wave
#define CHUNKS (NODES / NW)      // 392
#define PART_STRIDE 20           // 16 acc + 1 z + pad (16B-aligned records)

// ---------------- x transpose: x[b][n][i] -> xT[n][b][i] ----------------
__global__ __launch_bounds__(256) void k_xpose(const float* __restrict__ x,
                                               float* __restrict__ xT) {
    int g = blockIdx.x * 256 + threadIdx.x;      // g in [0, NODES*BATCH)
    int b = g & 63;
    int n = g >> 6;
    const float* xp = x + (size_t)b * (NODES * CIN) + (size_t)n * CIN;
    float4 a0 = *reinterpret_cast<const float4*>(xp);
    float4 a1 = *reinterpret_cast<const float4*>(xp + 4);
    float4* op = reinterpret_cast<float4*>(xT + (size_t)g * 8);
    op[0] = a0;
    op[1] = a1;
}

// ---------------- fused routing pass ----------------
// wave = 64 lanes = 64 batch entries; each wave owns (c, chunk of NW nodes).
// PASS 0: uniform weights (w=1). PASS>0: w = exp(dot(u_hat, vsum)).
template<int PASS>
__global__ __launch_bounds__(256) void k_pass(const float* __restrict__ xT,
                                              const float* __restrict__ W,
                                              const float* __restrict__ vsum,
                                              float* __restrict__ part) {
    int wid  = blockIdx.x * 4 + (threadIdx.x >> 6);   // 0 .. 3919
    int lane = threadIdx.x & 63;                       // = b
    int c    = wid % NCAPS;                            // c fastest: x-chunk L2 reuse
    int ch   = wid / NCAPS;                            // 0 .. 391
    int n0   = ch * NW;

    float vs[COUT];
    if (PASS > 0) {
        const float* vp = vsum + ((size_t)(c * BATCH) + lane) * COUT;
        #pragma unroll
        for (int o = 0; o < COUT; ++o) vs[o] = vp[o];
    }

    float acc[COUT];
    #pragma unroll
    for (int o = 0; o < COUT; ++o) acc[o] = 0.f;
    float z = 0.f;

    for (int nn = 0; nn < NW; ++nn) {
        int n = n0 + nn;
        // lane-private x row (coalesced: lane stride 32B)
        const float4* xp = reinterpret_cast<const float4*>(xT + ((size_t)n * 64 + lane) * 8);
        float4 xa = xp[0], xb = xp[1];
        float xv[8] = {xa.x, xa.y, xa.z, xa.w, xb.x, xb.y, xb.z, xb.w};

        // wave-uniform W row -> scalar loads via constant cache
        int nu = __builtin_amdgcn_readfirstlane(n);
        const float* __restrict__ wp = W + ((size_t)c * NODES + nu) * (CIN * COUT);

        float u[COUT];
        #pragma unroll
        for (int o = 0; o < COUT; ++o) u[o] = 0.f;
        #pragma unroll
        for (int i = 0; i < CIN; ++i) {
            float xi = xv[i];
            #pragma unroll
            for (int o = 0; o < COUT; ++o)
                u[o] = fmaf(xi, wp[i * COUT + o], u[o]);
        }

        if (PASS == 0) {
            #pragma unroll
            for (int o = 0; o < COUT; ++o) acc[o] += u[o];
            z += 1.f;
        } else {
            float lg = 0.f;
            #pragma unroll
            for (int o = 0; o < COUT; ++o) lg = fmaf(u[o], vs[o], lg);
            float w = __expf(lg);          // |lg| < ~22 worst case: safe without max-sub
            z += w;
            #pragma unroll
            for (int o = 0; o < COUT; ++o) acc[o] = fmaf(w, u[o], acc[o]);
        }
    }

    float* pp = part + ((size_t)((c * CHUNKS + ch) * BATCH) + lane) * PART_STRIDE;
    #pragma unroll
    for (int q = 0; q < 4; ++q) {
        reinterpret_cast<float4*>(pp)[q] =
            make_float4(acc[q * 4 + 0], acc[q * 4 + 1], acc[q * 4 + 2], acc[q * 4 + 3]);
    }
    pp[16] = z;
}

// ---------------- merge partials, squash, update vsum / write out ----------------
template<int PASS>
__global__ __launch_bounds__(256) void k_merge(const float* __restrict__ part,
                                               float* __restrict__ vsum,
                                               float* __restrict__ out) {
    int w    = blockIdx.x * 4 + (threadIdx.x >> 6);   // 0 .. 639  ( (c,b) pair )
    int lane = threadIdx.x & 63;
    if (w >= NCAPS * BATCH) return;
    int c = w / BATCH;
    int b = w % BATCH;

    float a[COUT];
    #pragma unroll
    for (int o = 0; o < COUT; ++o) a[o] = 0.f;
    float z = 0.f;

    for (int ch = lane; ch < CHUNKS; ch += 64) {
        const float* pp = part + ((size_t)((c * CHUNKS + ch) * BATCH) + b) * PART_STRIDE;
        #pragma unroll
        for (int o = 0; o < COUT; ++o) a[o] += pp[o];
        z += pp[16];
    }

    #pragma unroll
    for (int off = 32; off >= 1; off >>= 1) {
        z += __shfl_xor(z, off);
        #pragma unroll
        for (int o = 0; o < COUT; ++o) a[o] += __shfl_xor(a[o], off);
    }

    if (lane == 0) {
        float s[COUT];
        float sn = 0.f;
        #pragma unroll
        for (int o = 0; o < COUT; ++o) { s[o] = a[o] / z; sn += s[o] * s[o]; }
        float scale = sn / ((1.f + sn) * sqrtf(sn));   // |s|^2/(1+|s|^2) * 1/|s|
        if (PASS == 0) {
            float* vp = vsum + ((size_t)(c * BATCH) + b) * COUT;
            #pragma unroll
            for (int o = 0; o < COUT; ++o) vp[o] = scale * s[o];
        } else if (PASS == 1) {
            float* vp = vsum + ((size_t)(c * BATCH) + b) * COUT;
            #pragma unroll
            for (int o = 0; o < COUT; ++o) vp[o] += scale * s[o];
        } else {
            float* op = out + ((size_t)(b * NCAPS + c)) * COUT;
            #pragma unroll
            for (int o = 0; o < COUT; ++o) op[o] = scale * s[o];
        }
    }
}

extern "C" void kernel_launch(void* const* d_in, const int* in_sizes, int n_in,
                              void* d_out, int out_size, void* d_ws, size_t ws_size,
                              hipStream_t stream) {
    const float* x = (const float*)d_in[0];   // [64, 6272, 8]
    const float* W = (const float*)d_in[1];   // [10, 6272, 8, 16]
    float* out = (float*)d_out;               // [64, 10, 1, 16]
    float* ws  = (float*)d_ws;

    // ws layout (floats): xT [6272*64*8] | part [10*392*64*20] | vsum [10*64*16]
    float* xT   = ws;
    float* part = ws + (size_t)NODES * BATCH * CIN;                    // +3,211,264
    float* vsum = part + (size_t)NCAPS * CHUNKS * BATCH * PART_STRIDE; // +5,017,600

    k_xpose<<<(NODES * BATCH) / 256, 256, 0, stream>>>(x, xT);

    k_pass<0><<<(NCAPS * CHUNKS) / 4, 256, 0, stream>>>(xT, W, vsum, part);
    k_merge<0><<<(NCAPS * BATCH) / 4, 256, 0, stream>>>(part, vsum, out);

    k_pass<1><<<(NCAPS * CHUNKS) / 4, 256, 0, stream>>>(xT, W, vsum, part);
    k_merge<1><<<(NCAPS * BATCH) / 4, 256, 0, stream>>>(part, vsum, out);

    k_pass<2><<<(NCAPS * CHUNKS) / 4, 256, 0, stream>>>(xT, W, vsum, part);
    k_merge<2><<<(NCAPS * BATCH) / 4, 256, 0, stream>>>(part, vsum, out);
}

// Round 3
// 205.198 us; speedup vs baseline: 1.7313x; 1.7313x over previous
//
#include <hip/hip_runtime.h>
#include <math.h>

#define NODES 6272
#define BATCH 64
#define NCAPS 10
#define CIN   8
#define COUT  16
#define NWB   16                 // nodes per block
#define NWW   4                  // nodes per wave (4 waves/block)
#define CHUNKS (NODES / NWB)     // 392
#define PART_STRIDE 20           // 16 acc + 1 z + pad

// ---------------- x transpose: x[b][n][i] -> xT[n][b][i] ----------------
__global__ __launch_bounds__(256) void k_xpose(const float* __restrict__ x,
                                               float* __restrict__ xT) {
    int g = blockIdx.x * 256 + threadIdx.x;      // g in [0, NODES*BATCH)
    int b = g & 63;
    int n = g >> 6;
    const float* xp = x + (size_t)b * (NODES * CIN) + (size_t)n * CIN;
    float4 a0 = *reinterpret_cast<const float4*>(xp);
    float4 a1 = *reinterpret_cast<const float4*>(xp + 4);
    float4* op = reinterpret_cast<float4*>(xT + (size_t)g * 8);
    op[0] = a0;
    op[1] = a1;
}

// ---------------- fused routing pass ----------------
// Block (256 thr, 4 waves) owns (c, 16-node chunk). W chunk staged in LDS.
// Each wave: 4 nodes, lanes = 64 batches. PASS 0: w=1. PASS>0: w=exp(dot(u,vsum)).
template<int PASS>
__global__ __launch_bounds__(256) void k_pass(const float* __restrict__ xT,
                                              const float* __restrict__ W,
                                              const float* __restrict__ vsum,
                                              float* __restrict__ part) {
    __shared__ float Wl[NWB * 128];        // 8 KB
    __shared__ float Rbuf[2][64][PART_STRIDE]; // 10 KB cross-wave reduce buffer

    int bid  = blockIdx.x;                 // 0 .. 3919
    int wid  = threadIdx.x >> 6;           // 0 .. 3
    int lane = threadIdx.x & 63;           // = b
    int c    = bid % NCAPS;                // c fastest: x-chunk L2 reuse
    int ch   = bid / NCAPS;                // 0 .. 391
    int n0   = ch * NWB;

    // stage W[c, n0..n0+16) -> LDS, coalesced float4
    {
        const float4* src = reinterpret_cast<const float4*>(
            W + ((size_t)c * NODES + n0) * (CIN * COUT));
        float4* dst = reinterpret_cast<float4*>(Wl);
        int t = threadIdx.x;
        dst[t]       = src[t];
        dst[t + 256] = src[t + 256];
    }

    float vs[COUT];
    if (PASS > 0) {
        const float* vp = vsum + ((size_t)(c * BATCH) + lane) * COUT;
        #pragma unroll
        for (int o = 0; o < COUT; ++o) vs[o] = vp[o];
    }

    __syncthreads();

    float acc[COUT];
    #pragma unroll
    for (int o = 0; o < COUT; ++o) acc[o] = 0.f;
    float z = 0.f;

    int nbase = wid * NWW;
    #pragma unroll 2
    for (int nn = 0; nn < NWW; ++nn) {
        int nl = nbase + nn;               // node within chunk
        int n  = n0 + nl;

        // lane-private x row (coalesced, 32B/lane)
        const float4* xp = reinterpret_cast<const float4*>(xT + ((size_t)n * 64 + lane) * 8);
        float4 xa = xp[0], xb = xp[1];
        float xv[8] = {xa.x, xa.y, xa.z, xa.w, xb.x, xb.y, xb.z, xb.w};

        const float4* wl = reinterpret_cast<const float4*>(Wl + nl * 128);

        float u[COUT];
        #pragma unroll
        for (int o = 0; o < COUT; ++o) u[o] = 0.f;
        #pragma unroll
        for (int i = 0; i < CIN; ++i) {
            float xi = xv[i];
            float4 w0 = wl[i * 4 + 0];
            float4 w1 = wl[i * 4 + 1];
            float4 w2 = wl[i * 4 + 2];
            float4 w3 = wl[i * 4 + 3];
            u[0]  = fmaf(xi, w0.x, u[0]);  u[1]  = fmaf(xi, w0.y, u[1]);
            u[2]  = fmaf(xi, w0.z, u[2]);  u[3]  = fmaf(xi, w0.w, u[3]);
            u[4]  = fmaf(xi, w1.x, u[4]);  u[5]  = fmaf(xi, w1.y, u[5]);
            u[6]  = fmaf(xi, w1.z, u[6]);  u[7]  = fmaf(xi, w1.w, u[7]);
            u[8]  = fmaf(xi, w2.x, u[8]);  u[9]  = fmaf(xi, w2.y, u[9]);
            u[10] = fmaf(xi, w2.z, u[10]); u[11] = fmaf(xi, w2.w, u[11]);
            u[12] = fmaf(xi, w3.x, u[12]); u[13] = fmaf(xi, w3.y, u[13]);
            u[14] = fmaf(xi, w3.z, u[14]); u[15] = fmaf(xi, w3.w, u[15]);
        }

        if (PASS == 0) {
            #pragma unroll
            for (int o = 0; o < COUT; ++o) acc[o] += u[o];
            z += 1.f;
        } else {
            float lg = 0.f;
            #pragma unroll
            for (int o = 0; o < COUT; ++o) lg = fmaf(u[o], vs[o], lg);
            float w = __expf(lg);          // |lg| < ~22 worst case: safe without max-sub
            z += w;
            #pragma unroll
            for (int o = 0; o < COUT; ++o) acc[o] = fmaf(w, u[o], acc[o]);
        }
    }

    // cross-wave reduce: 4 waves -> 1 record per block
    if (wid >= 2) {
        float* rp = &Rbuf[wid - 2][lane][0];
        #pragma unroll
        for (int q = 0; q < 4; ++q)
            reinterpret_cast<float4*>(rp)[q] =
                make_float4(acc[q*4+0], acc[q*4+1], acc[q*4+2], acc[q*4+3]);
        rp[16] = z;
    }
    __syncthreads();
    if (wid < 2) {
        const float* rp = &Rbuf[wid][lane][0];
        #pragma unroll
        for (int o = 0; o < COUT; ++o) acc[o] += rp[o];
        z += rp[16];
    }
    __syncthreads();
    if (wid == 1) {
        float* rp = &Rbuf[0][lane][0];
        #pragma unroll
        for (int q = 0; q < 4; ++q)
            reinterpret_cast<float4*>(rp)[q] =
                make_float4(acc[q*4+0], acc[q*4+1], acc[q*4+2], acc[q*4+3]);
        rp[16] = z;
    }
    __syncthreads();
    if (wid == 0) {
        const float* rp = &Rbuf[0][lane][0];
        #pragma unroll
        for (int o = 0; o < COUT; ++o) acc[o] += rp[o];
        z += rp[16];

        float* pp = part + ((size_t)bid * BATCH + lane) * PART_STRIDE;
        #pragma unroll
        for (int q = 0; q < 4; ++q)
            reinterpret_cast<float4*>(pp)[q] =
                make_float4(acc[q*4+0], acc[q*4+1], acc[q*4+2], acc[q*4+3]);
        pp[16] = z;
    }
}

// ---------------- merge partials, squash, update vsum / write out ----------------
// Block (256 thr) per (c,b): threads sum chunk records, shuffle+LDS reduce, squash.
template<int PASS>
__global__ __launch_bounds__(256) void k_merge(const float* __restrict__ part,
                                               float* __restrict__ vsum,
                                               float* __restrict__ out) {
    __shared__ float R[3][PART_STRIDE];
    int bid = blockIdx.x;                  // 0..639 = c*64 + b
    int c = bid >> 6;
    int b = bid & 63;
    int t = threadIdx.x;

    float a[COUT];
    #pragma unroll
    for (int o = 0; o < COUT; ++o) a[o] = 0.f;
    float z = 0.f;

    for (int ch = t; ch < CHUNKS; ch += 256) {
        // record index for (c,ch) is ch*NCAPS + c (k_pass bid ordering)
        const float* pp = part + ((size_t)(ch * NCAPS + c) * BATCH + b) * PART_STRIDE;
        float4 q0 = reinterpret_cast<const float4*>(pp)[0];
        float4 q1 = reinterpret_cast<const float4*>(pp)[1];
        float4 q2 = reinterpret_cast<const float4*>(pp)[2];
        float4 q3 = reinterpret_cast<const float4*>(pp)[3];
        a[0]+=q0.x; a[1]+=q0.y; a[2]+=q0.z; a[3]+=q0.w;
        a[4]+=q1.x; a[5]+=q1.y; a[6]+=q1.z; a[7]+=q1.w;
        a[8]+=q2.x; a[9]+=q2.y; a[10]+=q2.z; a[11]+=q2.w;
        a[12]+=q3.x; a[13]+=q3.y; a[14]+=q3.z; a[15]+=q3.w;
        z += pp[16];
    }

    #pragma unroll
    for (int off = 32; off >= 1; off >>= 1) {
        z += __shfl_xor(z, off);
        #pragma unroll
        for (int o = 0; o < COUT; ++o) a[o] += __shfl_xor(a[o], off);
    }

    int wid = t >> 6, lane = t & 63;
    if (lane == 0 && wid > 0) {
        #pragma unroll
        for (int o = 0; o < COUT; ++o) R[wid - 1][o] = a[o];
        R[wid - 1][16] = z;
    }
    __syncthreads();
    if (t == 0) {
        #pragma unroll
        for (int r = 0; r < 3; ++r) {
            #pragma unroll
            for (int o = 0; o < COUT; ++o) a[o] += R[r][o];
            z += R[r][16];
        }
        float s[COUT];
        float sn = 0.f;
        #pragma unroll
        for (int o = 0; o < COUT; ++o) { s[o] = a[o] / z; sn += s[o] * s[o]; }
        float scale = sn / ((1.f + sn) * sqrtf(sn));   // |s|^2/(1+|s|^2) * 1/|s|
        if (PASS == 0) {
            float* vp = vsum + ((size_t)(c * BATCH) + b) * COUT;
            #pragma unroll
            for (int o = 0; o < COUT; ++o) vp[o] = scale * s[o];
        } else if (PASS == 1) {
            float* vp = vsum + ((size_t)(c * BATCH) + b) * COUT;
            #pragma unroll
            for (int o = 0; o < COUT; ++o) vp[o] += scale * s[o];
        } else {
            float* op = out + ((size_t)(b * NCAPS + c)) * COUT;
            #pragma unroll
            for (int o = 0; o < COUT; ++o) op[o] = scale * s[o];
        }
    }
}

extern "C" void kernel_launch(void* const* d_in, const int* in_sizes, int n_in,
                              void* d_out, int out_size, void* d_ws, size_t ws_size,
                              hipStream_t stream) {
    const float* x = (const float*)d_in[0];   // [64, 6272, 8]
    const float* W = (const float*)d_in[1];   // [10, 6272, 8, 16]
    float* out = (float*)d_out;               // [64, 10, 1, 16]
    float* ws  = (float*)d_ws;

    // ws layout (floats): xT [6272*64*8] | part [3920*64*20] | vsum [10*64*16]
    float* xT   = ws;
    float* part = ws + (size_t)NODES * BATCH * CIN;
    float* vsum = part + (size_t)NCAPS * CHUNKS * BATCH * PART_STRIDE;

    k_xpose<<<(NODES * BATCH) / 256, 256, 0, stream>>>(x, xT);

    k_pass<0><<<NCAPS * CHUNKS, 256, 0, stream>>>(xT, W, vsum, part);
    k_merge<0><<<NCAPS * BATCH, 256, 0, stream>>>(part, vsum, out);

    k_pass<1><<<NCAPS * CHUNKS, 256, 0, stream>>>(xT, W, vsum, part);
    k_merge<1><<<NCAPS * BATCH, 256, 0, stream>>>(part, vsum, out);

    k_pass<2><<<NCAPS * CHUNKS, 256, 0, stream>>>(xT, W, vsum, part);
    k_merge<2><<<NCAPS * BATCH, 256, 0, stream>>>(part, vsum, out);
}